// Round 4
// baseline (6967.944 us; speedup 1.0000x reference)
//
#include <hip/hip_runtime.h>
#include <cstdint>

#define T_STEPS 1024
#define BATCH   32
#define DIM     1024
#define RANK    128
#define BD      (BATCH*DIM)            // 32768
#define TBD     ((size_t)T_STEPS*BD)   // 33554432

typedef _Float16 half2v __attribute__((ext_vector_type(2)));

__device__ __forceinline__ float dot2f(uint32_t a, uint32_t b, float acc) {
#if __has_builtin(__builtin_amdgcn_fdot2)
  return __builtin_amdgcn_fdot2(__builtin_bit_cast(half2v, a),
                                __builtin_bit_cast(half2v, b), acc, false);
#else
  half2v xx = __builtin_bit_cast(half2v, a);
  half2v yy = __builtin_bit_cast(half2v, b);
  return acc + (float)xx[0]*(float)yy[0] + (float)xx[1]*(float)yy[1];
#endif
}

__device__ __forceinline__ float dot2x4(uint4 w, uint4 h, float acc) {
  acc = dot2f(w.x, h.x, acc); acc = dot2f(w.y, h.y, acc);
  acc = dot2f(w.z, h.z, acc); acc = dot2f(w.w, h.w, acc);
  return acc;
}

__device__ __forceinline__ uint16_t f16b(float x) {
  _Float16 h = (_Float16)x;
  return __builtin_bit_cast(unsigned short, h);
}
__device__ __forceinline__ uint32_t pack2(float a, float b) {
  return (uint32_t)f16b(a) | ((uint32_t)f16b(b) << 16);
}
__device__ __forceinline__ float fast_tanh(float x) {
  float e = __expf(2.0f*x);
  return 1.0f - 2.0f/(e + 1.0f);
}
__device__ __forceinline__ float fast_silu(float zz) {
  return zz / (1.0f + __expf(-zz));
}

// quad_perm broadcast of lane K (0..3) within each quad — VALU pipe, no LDS.
template<int K>
__device__ __forceinline__ uint32_t qbcast(uint32_t v) {
  return (uint32_t)__builtin_amdgcn_mov_dpp((int)v, K*0x55, 0xf, 0xf, true);
}
template<int K>
__device__ __forceinline__ uint4 qbcast4(uint4 v) {
  uint4 r;
  r.x = qbcast<K>(v.x); r.y = qbcast<K>(v.y);
  r.z = qbcast<K>(v.z); r.w = qbcast<K>(v.w);
  return r;
}

// barrier that does NOT drain vmcnt (only LDS ordering needed between phases)
__device__ __forceinline__ void lds_barrier() {
  asm volatile("s_waitcnt lgkmcnt(0)" ::: "memory");
  __builtin_amdgcn_s_barrier();
  __builtin_amdgcn_sched_barrier(0);
}

// ---------------------------------------------------------------------------
// K0: pack weights to f16 pairs in ws (s folded into U), h0 -> h-slot 0.
// ws layout (uint32 words):
//   [0]      vhw  [128][512]   V_h f16 pairs (row-major, word = d-pair)
//   [65536]  uhwA [16][512][4] U'_h EVEN rows, lane-swizzled:
//                              uint4 j of row 2l at word 65536 + j*2048 + l*4
//   [98304]  uhwB [16][512][4] U'_h ODD rows, same swizzle (row 2l+1)
//   [131072] vxw  [128][512]
//   [196608] uxw  [1024][64]   (plain pair layout, used by inp_kernel)
// ---------------------------------------------------------------------------
__global__ void prep_kernel(const float* __restrict__ Uh, const float* __restrict__ Vh,
                            const float* __restrict__ sh, const float* __restrict__ Ux,
                            const float* __restrict__ Vx, const float* __restrict__ sx,
                            const float* __restrict__ h0, uint32_t* __restrict__ ws32,
                            float* __restrict__ hout) {
  int i = blockIdx.x*blockDim.x + threadIdx.x;
  int n = gridDim.x*blockDim.x;
  for (int p = i; p < 65536; p += n) {
    int r = p >> 9, dp = p & 511;
    ws32[p] = pack2(Vh[r*1024 + 2*dp], Vh[r*1024 + 2*dp + 1]);
  }
  for (int p = i; p < 65536; p += n) {
    int d = p >> 6, k = p & 63;   // word k of row d = pairs (2k, 2k+1)
    uint32_t w = pack2(Uh[d*128 + 2*k]   * sh[2*k],
                       Uh[d*128 + 2*k+1] * sh[2*k+1]);
    int j = k >> 2, kk = k & 3, lane = d >> 1;
    int base = (d & 1) ? 98304 : 65536;
    ws32[base + j*2048 + lane*4 + kk] = w;
  }
  for (int p = i; p < 65536; p += n) {
    int r = p >> 9, dp = p & 511;
    ws32[131072 + p] = pack2(Vx[r*1024 + 2*dp], Vx[r*1024 + 2*dp + 1]);
  }
  for (int p = i; p < 65536; p += n) {
    int d = p >> 6, rp = p & 63;
    ws32[196608 + p] = pack2(Ux[d*128 + 2*rp]   * sx[2*rp],
                             Ux[d*128 + 2*rp+1] * sx[2*rp+1]);
  }
  for (int p = i; p < BD; p += n) hout[p] = h0[p];
}

// ---------------------------------------------------------------------------
// K1: input branch. One WG per timestep t.
// v4: lane remap q4=l&3 (b-offset), r=l>>2 -> xs reads conflict-free
// (distinct b's within a quad land on distinct bank quads).
// ---------------------------------------------------------------------------
__global__ __launch_bounds__(512, 4) void inp_kernel(
    const float* __restrict__ x, const uint32_t* __restrict__ ws32,
    const float* __restrict__ bias, float* __restrict__ hout) {
  const int t = blockIdx.x;
  const int l = threadIdx.x;  // 0..511
  __shared__ __attribute__((aligned(16))) uint32_t xs[32*516];
  __shared__ __attribute__((aligned(16))) uint16_t svx[BATCH*RANK];

  const float4* xg = (const float4*)(x + (size_t)t*BD);
  #pragma unroll
  for (int k = 0; k < 16; k++) {
    int i = l + 512*k;
    float4 v = xg[i];
    int bb = i >> 8;
    int d4 = i & 255;
    xs[bb*516 + d4*2]     = pack2(v.x, v.y);
    xs[bb*516 + d4*2 + 1] = pack2(v.z, v.w);
  }
  __syncthreads();

  const int q4 = l & 3;       // b offset within quad
  const int r  = l >> 2;      // 0..127
  const uint4* wrow = (const uint4*)(ws32 + 131072 + r*512);
  float acc0[8], acc1[8];
  #pragma unroll
  for (int bi = 0; bi < 8; bi++) { acc0[bi] = 0.f; acc1[bi] = 0.f; }
  #pragma unroll 4
  for (int J = 0; J < 128; J += 2) {
    uint4 w0 = wrow[J];
    uint4 w1 = wrow[J+1];
    #pragma unroll
    for (int bi = 0; bi < 8; bi++) {
      const uint4* xrow = (const uint4*)(xs + (4*bi + q4)*516);
      uint4 h0v = xrow[J];
      acc0[bi] = dot2f(w0.x, h0v.x, acc0[bi]);
      acc0[bi] = dot2f(w0.y, h0v.y, acc0[bi]);
      acc0[bi] = dot2f(w0.z, h0v.z, acc0[bi]);
      acc0[bi] = dot2f(w0.w, h0v.w, acc0[bi]);
      uint4 h1v = xrow[J+1];
      acc1[bi] = dot2f(w1.x, h1v.x, acc1[bi]);
      acc1[bi] = dot2f(w1.y, h1v.y, acc1[bi]);
      acc1[bi] = dot2f(w1.z, h1v.z, acc1[bi]);
      acc1[bi] = dot2f(w1.w, h1v.w, acc1[bi]);
    }
  }
  #pragma unroll
  for (int bi = 0; bi < 8; bi++)
    svx[(4*bi + q4)*RANK + r] = f16b(acc0[bi] + acc1[bi]);
  __syncthreads();

  const uint4* svx4 = (const uint4*)svx;
  float accb[BATCH];
  #pragma unroll 1
  for (int dd = 0; dd < 2; dd++) {
    int d = l + dd*512;
    const uint4* urow = (const uint4*)(ws32 + 196608 + d*64);
    #pragma unroll
    for (int bi = 0; bi < BATCH; bi++) accb[bi] = 0.f;
    #pragma unroll
    for (int RP = 0; RP < 16; RP++) {
      uint4 w = urow[RP];
      #pragma unroll
      for (int bi = 0; bi < BATCH; bi++) {
        uint4 sv = svx4[bi*16 + RP];
        accb[bi] = dot2f(w.x, sv.x, accb[bi]);
        accb[bi] = dot2f(w.y, sv.y, accb[bi]);
        accb[bi] = dot2f(w.z, sv.z, accb[bi]);
        accb[bi] = dot2f(w.w, sv.w, accb[bi]);
      }
    }
    float bv = bias[d];
    float* cslot = hout + (size_t)(t+1)*BD + d;
    #pragma unroll
    for (int bi = 0; bi < BATCH; bi++)
      cslot[(size_t)bi*DIM] = accb[bi] + bv;
  }
}

// ---------------------------------------------------------------------------
// K2: recurrence v4. One WG (512 thr, 2 waves/SIMD) per batch element.
//  - V_h ENTIRELY in registers: lane (R8=l>>5, W=l&31) holds rows
//    [8*R8, 8*R8+8) x pairs [16W, 16W+16) = 32 uint4 = 128 VGPRs.
//    Phase A h-read: only 4 ds_read_b128/lane (stride-5-uint4 staggered hbuf).
//  - U'_h streamed from L2 each step (constant, lane-swizzled coalesced
//    layout), double-quarter prefetch; VMEM pipe, zero DS cost.
//  - svh broadcast: quad-cooperative read (4 b128) + v_mov_dpp quad_perm.
//  - reduce-scatter tree over 32-lane row groups (9 shfl).
// ---------------------------------------------------------------------------
__global__ __launch_bounds__(512, 2) void rec_kernel(
    const uint32_t* __restrict__ ws32, const float* __restrict__ z,
    float* __restrict__ outb) {
  const int b  = blockIdx.x;
  const int l  = threadIdx.x;  // 0..511
  const int W  = l & 31;
  const int R8 = l >> 5;       // 0..15
  const int m  = l & 3;
  float* hout = outb + TBD;
  const uint32_t* vhw = ws32;

  __shared__ __attribute__((aligned(16))) uint4    hbuf[32*5];  // 2.5 KB staggered
  __shared__ __attribute__((aligned(16))) uint32_t svh32[64];   // 256 B

  // V fragments -> regs (128 VGPRs)
  uint4 vw[8][4];
  #pragma unroll
  for (int r = 0; r < 8; r++) {
    const uint4* src = (const uint4*)(vhw + (size_t)(8*R8 + r)*512 + W*16);
    #pragma unroll
    for (int c = 0; c < 4; c++) vw[r][c] = src[c];
  }
  // init hbuf from h0 (pair p=l at word 20*(p>>4) + (p&15))
  {
    const float2 v = ((const float2*)(hout + (size_t)b*DIM))[l];
    ((uint32_t*)hbuf)[20*(l>>4) + (l&15)] = pack2(v.x, v.y);
  }
  __syncthreads();

  const float2* zp2 = (const float2*)(z + (size_t)b*DIM) + l;
  float2*       cp2 = (float2*)(hout + BD + (size_t)b*DIM) + l;
  float2*       op2 = (float2*)(outb + (size_t)b*DIM) + l;
  const uint4*  uAp = (const uint4*)(ws32 + 65536) + l;   // + j*512 per slot
  const uint4*  uBp = (const uint4*)(ws32 + 98304) + l;
  const uint4*  hb4 = hbuf + W*5;
  const uint4*  svh4 = (const uint4*)svh32;

  #pragma unroll 1
  for (int t = 0; t < T_STEPS; t++) {
    // prefetch c (slot t+1), z (slot t)
    float2 cc = *cp2;
    float2 zz = *zp2;
    // prefetch U quarters 0,1 (slots 0..3, 4..7) — constant data, L2-hit
    uint4 uA0[4], uB0[4], uA1[4], uB1[4];
    #pragma unroll
    for (int i = 0; i < 4; i++) { uA0[i] = uAp[(i)*512];     uB0[i] = uBp[(i)*512]; }
    #pragma unroll
    for (int i = 0; i < 4; i++) { uA1[i] = uAp[(4+i)*512];   uB1[i] = uBp[(4+i)*512]; }

    // ---- phase A: 8 rows x 16 pairs from registers, h via 4 b128 ----
    float a[8] = {0.f,0.f,0.f,0.f,0.f,0.f,0.f,0.f};
    #pragma unroll
    for (int c = 0; c < 4; c++) {
      uint4 hv = hb4[c];
      #pragma unroll
      for (int r = 0; r < 8; r++) a[r] = dot2x4(vw[r][c], hv, a[r]);
    }
    // reduce-scatter: lane (R8, W) -> total for row 8*R8 + (W&7)
    float b4[4];
    {
      const bool s0 = (W & 1);
      #pragma unroll
      for (int i = 0; i < 4; i++) {
        float keep = s0 ? a[2*i+1] : a[2*i];
        float send = s0 ? a[2*i]   : a[2*i+1];
        b4[i] = keep + __shfl_xor(send, 1);
      }
    }
    float c2[2];
    {
      const bool s1 = (W >> 1) & 1;
      #pragma unroll
      for (int i = 0; i < 2; i++) {
        float keep = s1 ? b4[2*i+1] : b4[2*i];
        float send = s1 ? b4[2*i]   : b4[2*i+1];
        c2[i] = keep + __shfl_xor(send, 2);
      }
    }
    float s;
    {
      const bool s2 = (W >> 2) & 1;
      float keep = s2 ? c2[1] : c2[0];
      float send = s2 ? c2[0] : c2[1];
      s = keep + __shfl_xor(send, 4);
    }
    s += __shfl_xor(s, 8);
    s += __shfl_xor(s, 16);
    if (W < 8) ((uint16_t*)svh32)[8*R8 + W] = f16b(s);
    lds_barrier();

    // ---- phase B: rows d=2l, 2l+1; svh via quad-read + DPP broadcast ----
    float p0 = 0.f, p1 = 0.f;
    // quarter 0
    {
      uint4 svm = svh4[m];
      uint4 s0v = qbcast4<0>(svm), s1v = qbcast4<1>(svm);
      uint4 s2v = qbcast4<2>(svm), s3v = qbcast4<3>(svm);
      p0 = dot2x4(uA0[0], s0v, p0); p1 = dot2x4(uB0[0], s0v, p1);
      p0 = dot2x4(uA0[1], s1v, p0); p1 = dot2x4(uB0[1], s1v, p1);
      p0 = dot2x4(uA0[2], s2v, p0); p1 = dot2x4(uB0[2], s2v, p1);
      p0 = dot2x4(uA0[3], s3v, p0); p1 = dot2x4(uB0[3], s3v, p1);
    }
    // issue quarter 2 into uA0/uB0
    #pragma unroll
    for (int i = 0; i < 4; i++) { uA0[i] = uAp[(8+i)*512]; uB0[i] = uBp[(8+i)*512]; }
    // quarter 1
    {
      uint4 svm = svh4[4 + m];
      uint4 s0v = qbcast4<0>(svm), s1v = qbcast4<1>(svm);
      uint4 s2v = qbcast4<2>(svm), s3v = qbcast4<3>(svm);
      p0 = dot2x4(uA1[0], s0v, p0); p1 = dot2x4(uB1[0], s0v, p1);
      p0 = dot2x4(uA1[1], s1v, p0); p1 = dot2x4(uB1[1], s1v, p1);
      p0 = dot2x4(uA1[2], s2v, p0); p1 = dot2x4(uB1[2], s2v, p1);
      p0 = dot2x4(uA1[3], s3v, p0); p1 = dot2x4(uB1[3], s3v, p1);
    }
    // issue quarter 3 into uA1/uB1
    #pragma unroll
    for (int i = 0; i < 4; i++) { uA1[i] = uAp[(12+i)*512]; uB1[i] = uBp[(12+i)*512]; }
    // quarter 2
    {
      uint4 svm = svh4[8 + m];
      uint4 s0v = qbcast4<0>(svm), s1v = qbcast4<1>(svm);
      uint4 s2v = qbcast4<2>(svm), s3v = qbcast4<3>(svm);
      p0 = dot2x4(uA0[0], s0v, p0); p1 = dot2x4(uB0[0], s0v, p1);
      p0 = dot2x4(uA0[1], s1v, p0); p1 = dot2x4(uB0[1], s1v, p1);
      p0 = dot2x4(uA0[2], s2v, p0); p1 = dot2x4(uB0[2], s2v, p1);
      p0 = dot2x4(uA0[3], s3v, p0); p1 = dot2x4(uB0[3], s3v, p1);
    }
    // quarter 3
    {
      uint4 svm = svh4[12 + m];
      uint4 s0v = qbcast4<0>(svm), s1v = qbcast4<1>(svm);
      uint4 s2v = qbcast4<2>(svm), s3v = qbcast4<3>(svm);
      p0 = dot2x4(uA1[0], s0v, p0); p1 = dot2x4(uB1[0], s0v, p1);
      p0 = dot2x4(uA1[1], s1v, p0); p1 = dot2x4(uB1[1], s1v, p1);
      p0 = dot2x4(uA1[2], s2v, p0); p1 = dot2x4(uB1[2], s2v, p1);
      p0 = dot2x4(uA1[3], s3v, p0); p1 = dot2x4(uB1[3], s3v, p1);
    }

    float hv0 = fast_tanh(p0 + cc.x);
    float hv1 = fast_tanh(p1 + cc.y);
    *cp2 = make_float2(hv0, hv1);                           // h[t+1] (f32 out)
    ((uint32_t*)hbuf)[20*(l>>4) + (l&15)] = pack2(hv0, hv1); // h for next step
    *op2 = make_float2(hv0 * fast_silu(zz.x), hv1 * fast_silu(zz.y));
    lds_barrier();

    cp2 += BD/2; zp2 += BD/2; op2 += BD/2;
  }
}

extern "C" void kernel_launch(void* const* d_in, const int* in_sizes, int n_in,
                              void* d_out, int out_size, void* d_ws, size_t ws_size,
                              hipStream_t stream) {
  const float* x  = (const float*)d_in[0];
  const float* z  = (const float*)d_in[1];
  const float* h0 = (const float*)d_in[2];
  const float* Uh = (const float*)d_in[3];
  const float* Vh = (const float*)d_in[4];
  const float* sh = (const float*)d_in[5];
  const float* Ux = (const float*)d_in[6];
  const float* Vx = (const float*)d_in[7];
  const float* sx = (const float*)d_in[8];
  const float* bb = (const float*)d_in[9];
  float* outb = (float*)d_out;
  uint32_t* ws32 = (uint32_t*)d_ws;   // needs 1 MiB

  prep_kernel<<<512, 256, 0, stream>>>(Uh, Vh, sh, Ux, Vx, sx, h0, ws32, outb + TBD);
  inp_kernel<<<T_STEPS, 512, 0, stream>>>(x, ws32, bb, outb + TBD);
  rec_kernel<<<BATCH, 512, 0, stream>>>(ws32, z, outb);
}

// Round 5
// 3355.245 us; speedup vs baseline: 2.0767x; 2.0767x over previous
//
#include <hip/hip_runtime.h>
#include <cstdint>

#define T_STEPS 1024
#define BATCH   32
#define DIM     1024
#define RANK    128
#define BD      (BATCH*DIM)            // 32768
#define TBD     ((size_t)T_STEPS*BD)   // 33554432

typedef _Float16 half2v __attribute__((ext_vector_type(2)));

__device__ __forceinline__ float dot2f(uint32_t a, uint32_t b, float acc) {
#if __has_builtin(__builtin_amdgcn_fdot2)
  return __builtin_amdgcn_fdot2(__builtin_bit_cast(half2v, a),
                                __builtin_bit_cast(half2v, b), acc, false);
#else
  half2v xx = __builtin_bit_cast(half2v, a);
  half2v yy = __builtin_bit_cast(half2v, b);
  return acc + (float)xx[0]*(float)yy[0] + (float)xx[1]*(float)yy[1];
#endif
}

__device__ __forceinline__ float dot2x4(uint4 w, uint4 h, float acc) {
  acc = dot2f(w.x, h.x, acc); acc = dot2f(w.y, h.y, acc);
  acc = dot2f(w.z, h.z, acc); acc = dot2f(w.w, h.w, acc);
  return acc;
}

__device__ __forceinline__ uint16_t f16b(float x) {
  _Float16 h = (_Float16)x;
  return __builtin_bit_cast(unsigned short, h);
}
__device__ __forceinline__ uint32_t pack2(float a, float b) {
  return (uint32_t)f16b(a) | ((uint32_t)f16b(b) << 16);
}
__device__ __forceinline__ float fast_tanh(float x) {
  float e = __expf(2.0f*x);
  return 1.0f - 2.0f/(e + 1.0f);
}
__device__ __forceinline__ float fast_silu(float zz) {
  return zz / (1.0f + __expf(-zz));
}

// quad_perm broadcast of lane K (0..3) within each quad — VALU pipe, no LDS.
template<int K>
__device__ __forceinline__ uint32_t qbcast(uint32_t v) {
  return (uint32_t)__builtin_amdgcn_mov_dpp((int)v, K*0x55, 0xf, 0xf, true);
}
template<int K>
__device__ __forceinline__ uint4 qbcast4(uint4 v) {
  uint4 r;
  r.x = qbcast<K>(v.x); r.y = qbcast<K>(v.y);
  r.z = qbcast<K>(v.z); r.w = qbcast<K>(v.w);
  return r;
}
// xor-1 / xor-2 neighbor fetch via DPP quad_perm (VALU, not DS pipe).
template<int CTRL>
__device__ __forceinline__ float dpp_xorf(float v) {
  int t = __builtin_amdgcn_mov_dpp(__builtin_bit_cast(int, v), CTRL, 0xf, 0xf, true);
  return __builtin_bit_cast(float, t);
}

// barrier that does NOT drain vmcnt (only LDS ordering needed between phases)
__device__ __forceinline__ void lds_barrier() {
  asm volatile("s_waitcnt lgkmcnt(0)" ::: "memory");
  __builtin_amdgcn_s_barrier();
  __builtin_amdgcn_sched_barrier(0);
}

// ---------------------------------------------------------------------------
// K0: pack weights to f16 pairs in ws (s folded into U), h0 -> h-slot 0.
// ws layout (uint32 words):
//   [0]      vhw  [128][512]  V_h f16 pairs (word = adjacent d-pair)
//   [65536]  uhw2 [1024][64]  U'_h INTERLEAVED column pairs:
//                             word k of row d = pack(U[d][k]*s[k], U[d][k+64]*s[k+64])
//   [131072] vxw  [128][512]
//   [196608] uxw  [1024][64]  (plain pair layout, used by inp_kernel)
// ---------------------------------------------------------------------------
__global__ void prep_kernel(const float* __restrict__ Uh, const float* __restrict__ Vh,
                            const float* __restrict__ sh, const float* __restrict__ Ux,
                            const float* __restrict__ Vx, const float* __restrict__ sx,
                            const float* __restrict__ h0, uint32_t* __restrict__ ws32,
                            float* __restrict__ hout) {
  int i = blockIdx.x*blockDim.x + threadIdx.x;
  int n = gridDim.x*blockDim.x;
  for (int p = i; p < 65536; p += n) {
    int r = p >> 9, dp = p & 511;
    ws32[p] = pack2(Vh[r*1024 + 2*dp], Vh[r*1024 + 2*dp + 1]);
  }
  for (int p = i; p < 65536; p += n) {
    int d = p >> 6, k = p & 63;
    ws32[65536 + p] = pack2(Uh[d*128 + k]      * sh[k],
                            Uh[d*128 + 64 + k] * sh[64 + k]);
  }
  for (int p = i; p < 65536; p += n) {
    int r = p >> 9, dp = p & 511;
    ws32[131072 + p] = pack2(Vx[r*1024 + 2*dp], Vx[r*1024 + 2*dp + 1]);
  }
  for (int p = i; p < 65536; p += n) {
    int d = p >> 6, rp = p & 63;
    ws32[196608 + p] = pack2(Ux[d*128 + 2*rp]   * sx[2*rp],
                             Ux[d*128 + 2*rp+1] * sx[2*rp+1]);
  }
  for (int p = i; p < BD; p += n) hout[p] = h0[p];
}

// ---------------------------------------------------------------------------
// K1: input branch. One WG per timestep t. (unchanged — next round's target)
// ---------------------------------------------------------------------------
__global__ __launch_bounds__(512, 4) void inp_kernel(
    const float* __restrict__ x, const uint32_t* __restrict__ ws32,
    const float* __restrict__ bias, float* __restrict__ hout) {
  const int t = blockIdx.x;
  const int l = threadIdx.x;  // 0..511
  __shared__ __attribute__((aligned(16))) uint32_t xs[32*516];
  __shared__ __attribute__((aligned(16))) uint16_t svx[BATCH*RANK];

  const float4* xg = (const float4*)(x + (size_t)t*BD);
  #pragma unroll
  for (int k = 0; k < 16; k++) {
    int i = l + 512*k;
    float4 v = xg[i];
    int bb = i >> 8;
    int d4 = i & 255;
    xs[bb*516 + d4*2]     = pack2(v.x, v.y);
    xs[bb*516 + d4*2 + 1] = pack2(v.z, v.w);
  }
  __syncthreads();

  const int q4 = l & 3;
  const int r  = l >> 2;
  const uint4* wrow = (const uint4*)(ws32 + 131072 + r*512);
  float acc0[8], acc1[8];
  #pragma unroll
  for (int bi = 0; bi < 8; bi++) { acc0[bi] = 0.f; acc1[bi] = 0.f; }
  #pragma unroll 4
  for (int J = 0; J < 128; J += 2) {
    uint4 w0 = wrow[J];
    uint4 w1 = wrow[J+1];
    #pragma unroll
    for (int bi = 0; bi < 8; bi++) {
      const uint4* xrow = (const uint4*)(xs + (4*bi + q4)*516);
      uint4 h0v = xrow[J];
      acc0[bi] = dot2f(w0.x, h0v.x, acc0[bi]);
      acc0[bi] = dot2f(w0.y, h0v.y, acc0[bi]);
      acc0[bi] = dot2f(w0.z, h0v.z, acc0[bi]);
      acc0[bi] = dot2f(w0.w, h0v.w, acc0[bi]);
      uint4 h1v = xrow[J+1];
      acc1[bi] = dot2f(w1.x, h1v.x, acc1[bi]);
      acc1[bi] = dot2f(w1.y, h1v.y, acc1[bi]);
      acc1[bi] = dot2f(w1.z, h1v.z, acc1[bi]);
      acc1[bi] = dot2f(w1.w, h1v.w, acc1[bi]);
    }
  }
  #pragma unroll
  for (int bi = 0; bi < 8; bi++)
    svx[(4*bi + q4)*RANK + r] = f16b(acc0[bi] + acc1[bi]);
  __syncthreads();

  const uint4* svx4 = (const uint4*)svx;
  float accb[BATCH];
  #pragma unroll 1
  for (int dd = 0; dd < 2; dd++) {
    int d = l + dd*512;
    const uint4* urow = (const uint4*)(ws32 + 196608 + d*64);
    #pragma unroll
    for (int bi = 0; bi < BATCH; bi++) accb[bi] = 0.f;
    #pragma unroll
    for (int RP = 0; RP < 16; RP++) {
      uint4 w = urow[RP];
      #pragma unroll
      for (int bi = 0; bi < BATCH; bi++) {
        uint4 sv = svx4[bi*16 + RP];
        accb[bi] = dot2f(w.x, sv.x, accb[bi]);
        accb[bi] = dot2f(w.y, sv.y, accb[bi]);
        accb[bi] = dot2f(w.z, sv.z, accb[bi]);
        accb[bi] = dot2f(w.w, sv.w, accb[bi]);
      }
    }
    float bv = bias[d];
    float* cslot = hout + (size_t)(t+1)*BD + d;
    #pragma unroll
    for (int bi = 0; bi < BATCH; bi++)
      cslot[(size_t)bi*DIM] = accb[bi] + bv;
  }
}

// ---------------------------------------------------------------------------
// K2: recurrence v5. One WG (512 thr = 8 waves, 2 waves/SIMD) per batch b.
// __launch_bounds__(512,1): 1 block/CU -> 256-VGPR budget (R4's (512,2) gave
// 128 = spill disaster; 2nd arg is blocks/CU on this compiler).
// Weight residency (512 KB total):
//   regs 384 KB: V rows 8R8+0..5 (96 VGPR) + U words 0..47 of rows 2l,2l+1 (96)
//   LDS  128 KB: V rows 8R8+6,7 (64 KB, gold interleave) + U words 48..63 (64 KB)
// Per-step DS instrs/wave: V 8 + h 4 + U 8 + svh 4 + writes ~2  (R3 had 48)
// Phase A: lane (R8=l>>5, W=l&31), 8 rows x 16-pair window; DPP xor1/2 +
// shfl xor4/8/16 reduce-scatter. Phase B: d=2l,2l+1; svh quad-read + DPP bcast.
// ---------------------------------------------------------------------------
__global__ __launch_bounds__(512, 1) void rec_kernel(
    const uint32_t* __restrict__ ws32, const float* __restrict__ z,
    float* __restrict__ outb) {
  const int b  = blockIdx.x;
  const int l  = threadIdx.x;  // 0..511
  const int W  = l & 31;
  const int R8 = l >> 5;       // 0..15
  const int m  = l & 3;
  float* hout = outb + TBD;
  const uint4* vhw4 = (const uint4*)ws32;            // V: row stride 128 uint4
  const uint4* uhw4 = (const uint4*)(ws32 + 65536);  // U: row stride 16 uint4

  __shared__ __attribute__((aligned(16))) uint4    vlds[4096];   // 64 KB
  __shared__ __attribute__((aligned(16))) uint4    ulds[4096];   // 64 KB
  __shared__ __attribute__((aligned(16))) uint4    hbuf[32*5];   // 2.5 KB staggered
  __shared__ __attribute__((aligned(16))) uint32_t svh32[64];    // 256 B

  // V rows 8R8+0..5, window [16W,16W+16) pairs -> regs (96 VGPRs)
  uint4 vw[6][4];
  #pragma unroll
  for (int r = 0; r < 6; r++) {
    #pragma unroll
    for (int c = 0; c < 4; c++) vw[r][c] = vhw4[(8*R8 + r)*128 + W*4 + c];
  }
  // V rows 8R8+6,7 -> vlds (interleaved: idx = R8*256 + rr*128 + c*32 + W)
  #pragma unroll
  for (int rr = 0; rr < 2; rr++) {
    #pragma unroll
    for (int c = 0; c < 4; c++)
      vlds[R8*256 + rr*128 + c*32 + W] = vhw4[(8*R8 + 6 + rr)*128 + W*4 + c];
  }
  // U rows 2l,2l+1 words 0..47 -> regs (96 VGPRs)
  uint4 uqr0[12], uqr1[12];
  #pragma unroll
  for (int J = 0; J < 12; J++) { uqr0[J] = uhw4[(2*l)*16 + J]; uqr1[J] = uhw4[(2*l+1)*16 + J]; }
  // U words 48..63 -> ulds (lane-major: ulds[J*512 + l], J<4: row 2l, J>=4: row 2l+1)
  #pragma unroll
  for (int J = 0; J < 8; J++)
    ulds[J*512 + l] = uhw4[(2*l + (J >> 2))*16 + 12 + (J & 3)];
  // init hbuf from h0 (pair p=l at word 20*(p>>4) + (p&15))
  {
    const float2 v = ((const float2*)(hout + (size_t)b*DIM))[l];
    ((uint32_t*)hbuf)[20*(l>>4) + (l&15)] = pack2(v.x, v.y);
  }
  __syncthreads();

  const float2* zp2 = (const float2*)(z + (size_t)b*DIM) + l;
  float2*       cp2 = (float2*)(hout + BD + (size_t)b*DIM) + l;
  float2*       op2 = (float2*)(outb + (size_t)b*DIM) + l;
  const uint4*  hb4  = hbuf + W*5;
  const uint4*  svh4 = (const uint4*)svh32;

  #pragma unroll 1
  for (int t = 0; t < T_STEPS; t++) {
    // ---- phase A: 8 rows (6 reg + 2 LDS) x 16-pair window ----
    uint4 vLa[4], vLb[4];
    #pragma unroll
    for (int c = 0; c < 4; c++) vLa[c] = vlds[R8*256 + c*32 + W];
    #pragma unroll
    for (int c = 0; c < 4; c++) vLb[c] = vlds[R8*256 + 128 + c*32 + W];
    float a[8] = {0.f,0.f,0.f,0.f,0.f,0.f,0.f,0.f};
    #pragma unroll
    for (int c = 0; c < 4; c++) {
      uint4 hvc = hb4[c];
      a[0] = dot2x4(vw[0][c], hvc, a[0]);
      a[1] = dot2x4(vw[1][c], hvc, a[1]);
      a[2] = dot2x4(vw[2][c], hvc, a[2]);
      a[3] = dot2x4(vw[3][c], hvc, a[3]);
      a[4] = dot2x4(vw[4][c], hvc, a[4]);
      a[5] = dot2x4(vw[5][c], hvc, a[5]);
      a[6] = dot2x4(vLa[c], hvc, a[6]);
      a[7] = dot2x4(vLb[c], hvc, a[7]);
    }
    // reduce-scatter: row 8R8+(W&7) total lands in every lane of its group
    float b4[4];
    {
      const bool s0 = (W & 1);
      #pragma unroll
      for (int i = 0; i < 4; i++) {
        float keep = s0 ? a[2*i+1] : a[2*i];
        float send = s0 ? a[2*i]   : a[2*i+1];
        b4[i] = keep + dpp_xorf<0xB1>(send);   // quad_perm(1,0,3,2) = xor1
      }
    }
    float c2[2];
    {
      const bool s1 = (W >> 1) & 1;
      #pragma unroll
      for (int i = 0; i < 2; i++) {
        float keep = s1 ? b4[2*i+1] : b4[2*i];
        float send = s1 ? b4[2*i]   : b4[2*i+1];
        c2[i] = keep + dpp_xorf<0x4E>(send);   // quad_perm(2,3,0,1) = xor2
      }
    }
    float s;
    {
      const bool s2 = (W >> 2) & 1;
      float keep = s2 ? c2[1] : c2[0];
      float send = s2 ? c2[0] : c2[1];
      s = keep + __shfl_xor(send, 4);
    }
    s += __shfl_xor(s, 8);
    s += __shfl_xor(s, 16);
    if (W < 8) {
      int row = 8*R8 + W;                         // 0..127
      int idx = ((row & 63) << 1) | (row >> 6);   // packed (g, g+64) halves
      ((uint16_t*)svh32)[idx] = f16b(s);
    }
    lds_barrier();

    // ---- phase B: rows d=2l,2l+1; svh quad-read + DPP broadcast ----
    uint4 uL0[4], uL1[4];
    #pragma unroll
    for (int i = 0; i < 4; i++) uL0[i] = ulds[i*512 + l];
    #pragma unroll
    for (int i = 0; i < 4; i++) uL1[i] = ulds[(4+i)*512 + l];
    float2 cc = *cp2;
    float2 zz = *zp2;
    float p0 = 0.f, p1 = 0.f;
    { // quarter 0: k4 0..3 (regs)
      uint4 svm = svh4[m];
      uint4 s0v = qbcast4<0>(svm), s1v = qbcast4<1>(svm),
            s2v = qbcast4<2>(svm), s3v = qbcast4<3>(svm);
      p0 = dot2x4(uqr0[0], s0v, p0); p1 = dot2x4(uqr1[0], s0v, p1);
      p0 = dot2x4(uqr0[1], s1v, p0); p1 = dot2x4(uqr1[1], s1v, p1);
      p0 = dot2x4(uqr0[2], s2v, p0); p1 = dot2x4(uqr1[2], s2v, p1);
      p0 = dot2x4(uqr0[3], s3v, p0); p1 = dot2x4(uqr1[3], s3v, p1);
    }
    { // quarter 1: k4 4..7 (regs)
      uint4 svm = svh4[4 + m];
      uint4 s0v = qbcast4<0>(svm), s1v = qbcast4<1>(svm),
            s2v = qbcast4<2>(svm), s3v = qbcast4<3>(svm);
      p0 = dot2x4(uqr0[4], s0v, p0); p1 = dot2x4(uqr1[4], s0v, p1);
      p0 = dot2x4(uqr0[5], s1v, p0); p1 = dot2x4(uqr1[5], s1v, p1);
      p0 = dot2x4(uqr0[6], s2v, p0); p1 = dot2x4(uqr1[6], s2v, p1);
      p0 = dot2x4(uqr0[7], s3v, p0); p1 = dot2x4(uqr1[7], s3v, p1);
    }
    { // quarter 2: k4 8..11 (regs)
      uint4 svm = svh4[8 + m];
      uint4 s0v = qbcast4<0>(svm), s1v = qbcast4<1>(svm),
            s2v = qbcast4<2>(svm), s3v = qbcast4<3>(svm);
      p0 = dot2x4(uqr0[8],  s0v, p0); p1 = dot2x4(uqr1[8],  s0v, p1);
      p0 = dot2x4(uqr0[9],  s1v, p0); p1 = dot2x4(uqr1[9],  s1v, p1);
      p0 = dot2x4(uqr0[10], s2v, p0); p1 = dot2x4(uqr1[10], s2v, p1);
      p0 = dot2x4(uqr0[11], s3v, p0); p1 = dot2x4(uqr1[11], s3v, p1);
    }
    { // quarter 3: k4 12..15 (LDS)
      uint4 svm = svh4[12 + m];
      uint4 s0v = qbcast4<0>(svm), s1v = qbcast4<1>(svm),
            s2v = qbcast4<2>(svm), s3v = qbcast4<3>(svm);
      p0 = dot2x4(uL0[0], s0v, p0); p1 = dot2x4(uL1[0], s0v, p1);
      p0 = dot2x4(uL0[1], s1v, p0); p1 = dot2x4(uL1[1], s1v, p1);
      p0 = dot2x4(uL0[2], s2v, p0); p1 = dot2x4(uL1[2], s2v, p1);
      p0 = dot2x4(uL0[3], s3v, p0); p1 = dot2x4(uL1[3], s3v, p1);
    }

    float hv0 = fast_tanh(p0 + cc.x);
    float hv1 = fast_tanh(p1 + cc.y);
    *cp2 = make_float2(hv0, hv1);                             // h[t+1] (f32 out)
    ((uint32_t*)hbuf)[20*(l>>4) + (l&15)] = pack2(hv0, hv1);  // h for next step
    *op2 = make_float2(hv0 * fast_silu(zz.x), hv1 * fast_silu(zz.y));
    lds_barrier();

    cp2 += BD/2; zp2 += BD/2; op2 += BD/2;
  }
}

extern "C" void kernel_launch(void* const* d_in, const int* in_sizes, int n_in,
                              void* d_out, int out_size, void* d_ws, size_t ws_size,
                              hipStream_t stream) {
  const float* x  = (const float*)d_in[0];
  const float* z  = (const float*)d_in[1];
  const float* h0 = (const float*)d_in[2];
  const float* Uh = (const float*)d_in[3];
  const float* Vh = (const float*)d_in[4];
  const float* sh = (const float*)d_in[5];
  const float* Ux = (const float*)d_in[6];
  const float* Vx = (const float*)d_in[7];
  const float* sx = (const float*)d_in[8];
  const float* bb = (const float*)d_in[9];
  float* outb = (float*)d_out;
  uint32_t* ws32 = (uint32_t*)d_ws;   // needs 1 MiB

  prep_kernel<<<512, 256, 0, stream>>>(Uh, Vh, sh, Ux, Vx, sx, h0, ws32, outb + TBD);
  inp_kernel<<<T_STEPS, 512, 0, stream>>>(x, ws32, bb, outb + TBD);
  rec_kernel<<<BATCH, 512, 0, stream>>>(ws32, z, outb);
}

// Round 6
// 2986.055 us; speedup vs baseline: 2.3335x; 1.1236x over previous
//
#include <hip/hip_runtime.h>
#include <cstdint>

#define T_STEPS 1024
#define BATCH   32
#define DIM     1024
#define RANK    128
#define BD      (BATCH*DIM)            // 32768
#define TBD     ((size_t)T_STEPS*BD)   // 33554432

typedef _Float16 half2v __attribute__((ext_vector_type(2)));

__device__ __forceinline__ float dot2f(uint32_t a, uint32_t b, float acc) {
#if __has_builtin(__builtin_amdgcn_fdot2)
  return __builtin_amdgcn_fdot2(__builtin_bit_cast(half2v, a),
                                __builtin_bit_cast(half2v, b), acc, false);
#else
  half2v xx = __builtin_bit_cast(half2v, a);
  half2v yy = __builtin_bit_cast(half2v, b);
  return acc + (float)xx[0]*(float)yy[0] + (float)xx[1]*(float)yy[1];
#endif
}

__device__ __forceinline__ float dot2x4(uint4 w, uint4 h, float acc) {
  acc = dot2f(w.x, h.x, acc); acc = dot2f(w.y, h.y, acc);
  acc = dot2f(w.z, h.z, acc); acc = dot2f(w.w, h.w, acc);
  return acc;
}

__device__ __forceinline__ uint16_t f16b(float x) {
  _Float16 h = (_Float16)x;
  return __builtin_bit_cast(unsigned short, h);
}
__device__ __forceinline__ uint32_t pack2(float a, float b) {
  return (uint32_t)f16b(a) | ((uint32_t)f16b(b) << 16);
}
__device__ __forceinline__ float fast_tanh(float x) {
  float e = __expf(2.0f*x);
  return 1.0f - 2.0f/(e + 1.0f);
}
__device__ __forceinline__ float fast_silu(float zz) {
  return zz / (1.0f + __expf(-zz));
}

// quad_perm broadcast of lane K (0..3) within each quad — VALU pipe, no LDS.
template<int K>
__device__ __forceinline__ uint32_t qbcast(uint32_t v) {
  return (uint32_t)__builtin_amdgcn_mov_dpp((int)v, K*0x55, 0xf, 0xf, true);
}
template<int K>
__device__ __forceinline__ uint4 qbcast4(uint4 v) {
  uint4 r;
  r.x = qbcast<K>(v.x); r.y = qbcast<K>(v.y);
  r.z = qbcast<K>(v.z); r.w = qbcast<K>(v.w);
  return r;
}
// xor-1 / xor-2 neighbor fetch via DPP quad_perm (VALU, not DS pipe).
template<int CTRL>
__device__ __forceinline__ float dpp_xorf(float v) {
  int t = __builtin_amdgcn_mov_dpp(__builtin_bit_cast(int, v), CTRL, 0xf, 0xf, true);
  return __builtin_bit_cast(float, t);
}

// barrier that does NOT drain vmcnt (only LDS ordering needed between phases)
__device__ __forceinline__ void lds_barrier() {
  asm volatile("s_waitcnt lgkmcnt(0)" ::: "memory");
  __builtin_amdgcn_s_barrier();
  __builtin_amdgcn_sched_barrier(0);
}

// ---------------------------------------------------------------------------
// K0: pack weights to f16 pairs in ws (s folded into U), h0 -> h-slot 0.
// ws layout (uint32 words):
//   [0]      vhw  [128][512]  V_h f16 pairs (word = adjacent d-pair)
//   [65536]  uhw2 [1024][64]  U'_h INTERLEAVED column pairs:
//                             word k of row d = pack(U[d][k]*s[k], U[d][k+64]*s[k+64])
//   [131072] vxw  [128][512]
//   [196608] uxw  [1024][64]  (plain pair layout, used by inp_kernel)
// ---------------------------------------------------------------------------
__global__ void prep_kernel(const float* __restrict__ Uh, const float* __restrict__ Vh,
                            const float* __restrict__ sh, const float* __restrict__ Ux,
                            const float* __restrict__ Vx, const float* __restrict__ sx,
                            const float* __restrict__ h0, uint32_t* __restrict__ ws32,
                            float* __restrict__ hout) {
  int i = blockIdx.x*blockDim.x + threadIdx.x;
  int n = gridDim.x*blockDim.x;
  for (int p = i; p < 65536; p += n) {
    int r = p >> 9, dp = p & 511;
    ws32[p] = pack2(Vh[r*1024 + 2*dp], Vh[r*1024 + 2*dp + 1]);
  }
  for (int p = i; p < 65536; p += n) {
    int d = p >> 6, k = p & 63;
    ws32[65536 + p] = pack2(Uh[d*128 + k]      * sh[k],
                            Uh[d*128 + 64 + k] * sh[64 + k]);
  }
  for (int p = i; p < 65536; p += n) {
    int r = p >> 9, dp = p & 511;
    ws32[131072 + p] = pack2(Vx[r*1024 + 2*dp], Vx[r*1024 + 2*dp + 1]);
  }
  for (int p = i; p < 65536; p += n) {
    int d = p >> 6, rp = p & 63;
    ws32[196608 + p] = pack2(Ux[d*128 + 2*rp]   * sx[2*rp],
                             Ux[d*128 + 2*rp+1] * sx[2*rp+1]);
  }
  for (int p = i; p < BD; p += n) hout[p] = h0[p];
}

// ---------------------------------------------------------------------------
// K1: input branch. One WG per timestep t. (unchanged)
// ---------------------------------------------------------------------------
__global__ __launch_bounds__(512, 4) void inp_kernel(
    const float* __restrict__ x, const uint32_t* __restrict__ ws32,
    const float* __restrict__ bias, float* __restrict__ hout) {
  const int t = blockIdx.x;
  const int l = threadIdx.x;  // 0..511
  __shared__ __attribute__((aligned(16))) uint32_t xs[32*516];
  __shared__ __attribute__((aligned(16))) uint16_t svx[BATCH*RANK];

  const float4* xg = (const float4*)(x + (size_t)t*BD);
  #pragma unroll
  for (int k = 0; k < 16; k++) {
    int i = l + 512*k;
    float4 v = xg[i];
    int bb = i >> 8;
    int d4 = i & 255;
    xs[bb*516 + d4*2]     = pack2(v.x, v.y);
    xs[bb*516 + d4*2 + 1] = pack2(v.z, v.w);
  }
  __syncthreads();

  const int q4 = l & 3;
  const int r  = l >> 2;
  const uint4* wrow = (const uint4*)(ws32 + 131072 + r*512);
  float acc0[8], acc1[8];
  #pragma unroll
  for (int bi = 0; bi < 8; bi++) { acc0[bi] = 0.f; acc1[bi] = 0.f; }
  #pragma unroll 4
  for (int J = 0; J < 128; J += 2) {
    uint4 w0 = wrow[J];
    uint4 w1 = wrow[J+1];
    #pragma unroll
    for (int bi = 0; bi < 8; bi++) {
      const uint4* xrow = (const uint4*)(xs + (4*bi + q4)*516);
      uint4 h0v = xrow[J];
      acc0[bi] = dot2f(w0.x, h0v.x, acc0[bi]);
      acc0[bi] = dot2f(w0.y, h0v.y, acc0[bi]);
      acc0[bi] = dot2f(w0.z, h0v.z, acc0[bi]);
      acc0[bi] = dot2f(w0.w, h0v.w, acc0[bi]);
      uint4 h1v = xrow[J+1];
      acc1[bi] = dot2f(w1.x, h1v.x, acc1[bi]);
      acc1[bi] = dot2f(w1.y, h1v.y, acc1[bi]);
      acc1[bi] = dot2f(w1.z, h1v.z, acc1[bi]);
      acc1[bi] = dot2f(w1.w, h1v.w, acc1[bi]);
    }
  }
  #pragma unroll
  for (int bi = 0; bi < 8; bi++)
    svx[(4*bi + q4)*RANK + r] = f16b(acc0[bi] + acc1[bi]);
  __syncthreads();

  const uint4* svx4 = (const uint4*)svx;
  float accb[BATCH];
  #pragma unroll 1
  for (int dd = 0; dd < 2; dd++) {
    int d = l + dd*512;
    const uint4* urow = (const uint4*)(ws32 + 196608 + d*64);
    #pragma unroll
    for (int bi = 0; bi < BATCH; bi++) accb[bi] = 0.f;
    #pragma unroll
    for (int RP = 0; RP < 16; RP++) {
      uint4 w = urow[RP];
      #pragma unroll
      for (int bi = 0; bi < BATCH; bi++) {
        uint4 sv = svx4[bi*16 + RP];
        accb[bi] = dot2f(w.x, sv.x, accb[bi]);
        accb[bi] = dot2f(w.y, sv.y, accb[bi]);
        accb[bi] = dot2f(w.z, sv.z, accb[bi]);
        accb[bi] = dot2f(w.w, sv.w, accb[bi]);
      }
    }
    float bv = bias[d];
    float* cslot = hout + (size_t)(t+1)*BD + d;
    #pragma unroll
    for (int bi = 0; bi < BATCH; bi++)
      cslot[(size_t)bi*DIM] = accb[bi] + bv;
  }
}

// ---------------------------------------------------------------------------
// K2: recurrence v6. One WG (512 thr = 8 waves, 2 waves/SIMD) per batch b.
// amdgpu_waves_per_eu(2,2): pin scheduler's occupancy target to 2 waves/EU
// -> 256-VGPR budget (R4/R5: heuristic chose 4 waves/EU -> 128 VGPR -> the
// 192 weight regs were rematerialized from L2 every step, ~6400 cyc/step).
// Weight residency (512 KB total):
//   regs 384 KB: V rows 8R8+0..5 (96 VGPR) + U words 0..47 of rows 2l,2l+1 (96)
//   LDS  128 KB: V rows 8R8+6,7 (64 KB, interleave) + U words 48..63 (64 KB)
// c/z loads hoisted to loop top (HBM latency hidden under phase A).
// Phase A: per-c pipelined LDS V loads; DPP xor1/2 + shfl xor4/8/16 reduce.
// Phase B: svh quad-read + one-at-a-time DPP broadcast; U-LDS staged in two
// 16-reg chunks (before quarters 1 and 2, consumed in quarter 3).
// ---------------------------------------------------------------------------
__global__ __launch_bounds__(512) __attribute__((amdgpu_waves_per_eu(2, 2)))
void rec_kernel(
    const uint32_t* __restrict__ ws32, const float* __restrict__ z,
    float* __restrict__ outb) {
  const int b  = blockIdx.x;
  const int l  = threadIdx.x;  // 0..511
  const int W  = l & 31;
  const int R8 = l >> 5;       // 0..15
  const int m  = l & 3;
  float* hout = outb + TBD;
  const uint4* vhw4 = (const uint4*)ws32;            // V: row stride 128 uint4
  const uint4* uhw4 = (const uint4*)(ws32 + 65536);  // U: row stride 16 uint4

  __shared__ __attribute__((aligned(16))) uint4    vlds[4096];   // 64 KB
  __shared__ __attribute__((aligned(16))) uint4    ulds[4096];   // 64 KB
  __shared__ __attribute__((aligned(16))) uint4    hbuf[32*5];   // 2.5 KB staggered
  __shared__ __attribute__((aligned(16))) uint32_t svh32[64];    // 256 B

  // V rows 8R8+0..5, window [16W,16W+16) pairs -> regs (96 VGPRs)
  uint4 vw[6][4];
  #pragma unroll
  for (int r = 0; r < 6; r++) {
    #pragma unroll
    for (int c = 0; c < 4; c++) vw[r][c] = vhw4[(8*R8 + r)*128 + W*4 + c];
  }
  // V rows 8R8+6,7 -> vlds (interleaved: idx = R8*256 + rr*128 + c*32 + W)
  #pragma unroll
  for (int rr = 0; rr < 2; rr++) {
    #pragma unroll
    for (int c = 0; c < 4; c++)
      vlds[R8*256 + rr*128 + c*32 + W] = vhw4[(8*R8 + 6 + rr)*128 + W*4 + c];
  }
  // U rows 2l,2l+1 words 0..47 -> regs (96 VGPRs)
  uint4 uqr0[12], uqr1[12];
  #pragma unroll
  for (int J = 0; J < 12; J++) { uqr0[J] = uhw4[(2*l)*16 + J]; uqr1[J] = uhw4[(2*l+1)*16 + J]; }
  // U words 48..63 -> ulds (lane-major: ulds[J*512 + l], J<4: row 2l, J>=4: row 2l+1)
  #pragma unroll
  for (int J = 0; J < 8; J++)
    ulds[J*512 + l] = uhw4[(2*l + (J >> 2))*16 + 12 + (J & 3)];
  // init hbuf from h0 (pair p=l at word 20*(p>>4) + (p&15))
  {
    const float2 v = ((const float2*)(hout + (size_t)b*DIM))[l];
    ((uint32_t*)hbuf)[20*(l>>4) + (l&15)] = pack2(v.x, v.y);
  }
  __syncthreads();

  const float2* zp2 = (const float2*)(z + (size_t)b*DIM) + l;
  float2*       cp2 = (float2*)(hout + BD + (size_t)b*DIM) + l;
  float2*       op2 = (float2*)(outb + (size_t)b*DIM) + l;
  const uint4*  hb4  = hbuf + W*5;
  const uint4*  svh4 = (const uint4*)svh32;
  const int vbase = R8*256;

  #pragma unroll 1
  for (int t = 0; t < T_STEPS; t++) {
    // ---- issue c (slot t+1) and z (slot t) loads: used at end of phase B,
    //      ~1500 cyc away -> HBM latency hidden ----
    float2 cc = *cp2;
    float2 zz = *zp2;

    // ---- phase A: 8 rows (6 reg + 2 LDS, per-c pipelined) x 16-pair window ----
    float a[8] = {0.f,0.f,0.f,0.f,0.f,0.f,0.f,0.f};
    uint4 vAc = vlds[vbase + W];
    uint4 vBc = vlds[vbase + 128 + W];
    uint4 hvc = hb4[0];
    #pragma unroll
    for (int c = 0; c < 4; c++) {
      uint4 vAn, vBn, hvn;
      if (c < 3) {
        vAn = vlds[vbase + (c+1)*32 + W];
        vBn = vlds[vbase + 128 + (c+1)*32 + W];
        hvn = hb4[c+1];
      }
      a[0] = dot2x4(vw[0][c], hvc, a[0]);
      a[1] = dot2x4(vw[1][c], hvc, a[1]);
      a[2] = dot2x4(vw[2][c], hvc, a[2]);
      a[3] = dot2x4(vw[3][c], hvc, a[3]);
      a[4] = dot2x4(vw[4][c], hvc, a[4]);
      a[5] = dot2x4(vw[5][c], hvc, a[5]);
      a[6] = dot2x4(vAc, hvc, a[6]);
      a[7] = dot2x4(vBc, hvc, a[7]);
      if (c < 3) { vAc = vAn; vBc = vBn; hvc = hvn; }
    }
    // reduce-scatter: row 8R8+(W&7) total lands in every lane of its group
    float b4[4];
    {
      const bool s0 = (W & 1);
      #pragma unroll
      for (int i = 0; i < 4; i++) {
        float keep = s0 ? a[2*i+1] : a[2*i];
        float send = s0 ? a[2*i]   : a[2*i+1];
        b4[i] = keep + dpp_xorf<0xB1>(send);   // quad_perm(1,0,3,2) = xor1
      }
    }
    float c2[2];
    {
      const bool s1 = (W >> 1) & 1;
      #pragma unroll
      for (int i = 0; i < 2; i++) {
        float keep = s1 ? b4[2*i+1] : b4[2*i];
        float send = s1 ? b4[2*i]   : b4[2*i+1];
        c2[i] = keep + dpp_xorf<0x4E>(send);   // quad_perm(2,3,0,1) = xor2
      }
    }
    float s;
    {
      const bool s2 = (W >> 2) & 1;
      float keep = s2 ? c2[1] : c2[0];
      float send = s2 ? c2[0] : c2[1];
      s = keep + __shfl_xor(send, 4);
    }
    s += __shfl_xor(s, 8);
    s += __shfl_xor(s, 16);
    if (W < 8) {
      int row = 8*R8 + W;                         // 0..127
      int idx = ((row & 63) << 1) | (row >> 6);   // packed (g, g+64) halves
      ((uint16_t*)svh32)[idx] = f16b(s);
    }
    lds_barrier();

    // ---- phase B: rows d=2l,2l+1; svh quad-read + DPP broadcast ----
    float p0 = 0.f, p1 = 0.f;
    { // quarter 0: k4 0..3 (regs)
      uint4 svm = svh4[m];
      uint4 sv;
      sv = qbcast4<0>(svm); p0 = dot2x4(uqr0[0], sv, p0); p1 = dot2x4(uqr1[0], sv, p1);
      sv = qbcast4<1>(svm); p0 = dot2x4(uqr0[1], sv, p0); p1 = dot2x4(uqr1[1], sv, p1);
      sv = qbcast4<2>(svm); p0 = dot2x4(uqr0[2], sv, p0); p1 = dot2x4(uqr1[2], sv, p1);
      sv = qbcast4<3>(svm); p0 = dot2x4(uqr0[3], sv, p0); p1 = dot2x4(uqr1[3], sv, p1);
    }
    uint4 uL0[4];
    #pragma unroll
    for (int i = 0; i < 4; i++) uL0[i] = ulds[i*512 + l];
    { // quarter 1: k4 4..7 (regs)
      uint4 svm = svh4[4 + m];
      uint4 sv;
      sv = qbcast4<0>(svm); p0 = dot2x4(uqr0[4], sv, p0); p1 = dot2x4(uqr1[4], sv, p1);
      sv = qbcast4<1>(svm); p0 = dot2x4(uqr0[5], sv, p0); p1 = dot2x4(uqr1[5], sv, p1);
      sv = qbcast4<2>(svm); p0 = dot2x4(uqr0[6], sv, p0); p1 = dot2x4(uqr1[6], sv, p1);
      sv = qbcast4<3>(svm); p0 = dot2x4(uqr0[7], sv, p0); p1 = dot2x4(uqr1[7], sv, p1);
    }
    uint4 uL1[4];
    #pragma unroll
    for (int i = 0; i < 4; i++) uL1[i] = ulds[(4+i)*512 + l];
    { // quarter 2: k4 8..11 (regs)
      uint4 svm = svh4[8 + m];
      uint4 sv;
      sv = qbcast4<0>(svm); p0 = dot2x4(uqr0[8],  sv, p0); p1 = dot2x4(uqr1[8],  sv, p1);
      sv = qbcast4<1>(svm); p0 = dot2x4(uqr0[9],  sv, p0); p1 = dot2x4(uqr1[9],  sv, p1);
      sv = qbcast4<2>(svm); p0 = dot2x4(uqr0[10], sv, p0); p1 = dot2x4(uqr1[10], sv, p1);
      sv = qbcast4<3>(svm); p0 = dot2x4(uqr0[11], sv, p0); p1 = dot2x4(uqr1[11], sv, p1);
    }
    { // quarter 3: k4 12..15 (LDS)
      uint4 svm = svh4[12 + m];
      uint4 sv;
      sv = qbcast4<0>(svm); p0 = dot2x4(uL0[0], sv, p0); p1 = dot2x4(uL1[0], sv, p1);
      sv = qbcast4<1>(svm); p0 = dot2x4(uL0[1], sv, p0); p1 = dot2x4(uL1[1], sv, p1);
      sv = qbcast4<2>(svm); p0 = dot2x4(uL0[2], sv, p0); p1 = dot2x4(uL1[2], sv, p1);
      sv = qbcast4<3>(svm); p0 = dot2x4(uL0[3], sv, p0); p1 = dot2x4(uL1[3], sv, p1);
    }

    float hv0 = fast_tanh(p0 + cc.x);
    float hv1 = fast_tanh(p1 + cc.y);
    *cp2 = make_float2(hv0, hv1);                             // h[t+1] (f32 out)
    ((uint32_t*)hbuf)[20*(l>>4) + (l&15)] = pack2(hv0, hv1);  // h for next step
    *op2 = make_float2(hv0 * fast_silu(zz.x), hv1 * fast_silu(zz.y));
    lds_barrier();

    cp2 += BD/2; zp2 += BD/2; op2 += BD/2;
  }
}

extern "C" void kernel_launch(void* const* d_in, const int* in_sizes, int n_in,
                              void* d_out, int out_size, void* d_ws, size_t ws_size,
                              hipStream_t stream) {
  const float* x  = (const float*)d_in[0];
  const float* z  = (const float*)d_in[1];
  const float* h0 = (const float*)d_in[2];
  const float* Uh = (const float*)d_in[3];
  const float* Vh = (const float*)d_in[4];
  const float* sh = (const float*)d_in[5];
  const float* Ux = (const float*)d_in[6];
  const float* Vx = (const float*)d_in[7];
  const float* sx = (const float*)d_in[8];
  const float* bb = (const float*)d_in[9];
  float* outb = (float*)d_out;
  uint32_t* ws32 = (uint32_t*)d_ws;   // needs 1 MiB

  prep_kernel<<<512, 256, 0, stream>>>(Uh, Vh, sh, Ux, Vx, sx, h0, ws32, outb + TBD);
  inp_kernel<<<T_STEPS, 512, 0, stream>>>(x, ws32, bb, outb + TBD);
  rec_kernel<<<BATCH, 512, 0, stream>>>(ws32, z, outb);
}